// Round 11
// baseline (138.565 us; speedup 1.0000x reference)
//
#include <hip/hip_runtime.h>
#include <stdint.h>

// MultiHeadAttention fused pipeline for MI355X (gfx950).
// B=2, S=2048, D=1024, H=16, dk=64. fp32 in/out, bf16 MFMA compute.

#define AS1 __attribute__((address_space(1)))
#define AS3 __attribute__((address_space(3)))

typedef unsigned short u16;
typedef short s16x8 __attribute__((ext_vector_type(8)));   // 8 bf16 (4 VGPRs) MFMA frag
typedef float f32x4 __attribute__((ext_vector_type(4)));   // 16x16 MFMA accumulator
typedef float f32x16 __attribute__((ext_vector_type(16))); // 32x32 MFMA accumulator
typedef u16   u16x4 __attribute__((ext_vector_type(4)));

#if defined(__has_builtin)
#if __has_builtin(__builtin_amdgcn_exp2f)
#define EXP2F(x) __builtin_amdgcn_exp2f(x)
#else
#define EXP2F(x) exp2f(x)
#endif
#else
#define EXP2F(x) exp2f(x)
#endif

__device__ __forceinline__ u16 f2b(float f) {  // fp32 -> bf16 RNE
  union { float f; uint32_t u; } v;
  v.f = f;
  uint32_t r = (v.u + 0x7fffu + ((v.u >> 16) & 1u)) >> 16;
  return (u16)r;
}

// packed fp32x2 -> bf16x2 (1 VALU op; no builtin on gfx950 -> inline asm, T12)
__device__ __forceinline__ uint32_t cvtpk(float lo, float hi) {
  uint32_t r;
  asm("v_cvt_pk_bf16_f32 %0, %1, %2" : "=v"(r) : "v"(lo), "v"(hi));
  return r;
}

__device__ __forceinline__ float max3f(float a, float b, float c) {
  float r;
  asm("v_max3_f32 %0, %1, %2, %3" : "=v"(r) : "v"(a), "v"(b), "v"(c));
  return r;
}

__device__ __forceinline__ f32x4 mfma16(s16x8 a, s16x8 b, f32x4 c) {
  return __builtin_amdgcn_mfma_f32_16x16x32_bf16(a, b, c, 0, 0, 0);
}

__device__ __forceinline__ f32x16 mfma32(s16x8 a, s16x8 b, f32x16 c) {
  return __builtin_amdgcn_mfma_f32_32x32x16_bf16(a, b, c, 0, 0, 0);
}

__device__ __forceinline__ s16x8 ld_g16(const u16* p) {
  return *reinterpret_cast<const s16x8*>(p);
}

// async global->LDS, 16B per lane. LDS dest must be WAVE-UNIFORM base; HW adds lane*16.
// Global SOURCE is per-lane -> swizzled layouts via pre-swizzled source (m173).
__device__ __forceinline__ void stage16(const u16* g, u16* lds_base) {
  __builtin_amdgcn_global_load_lds((const AS1 unsigned int*)g,
                                   (AS3 unsigned int*)lds_base, 16, 0, 0);
}

// ---------------------------------------------------------------- fused fp32 -> bf16 (all 7 tensors)
struct CvtArgs {
  const float* src[7];
  u16* dst[7];
  int cum[8];   // cumulative block ranges
};

__global__ __launch_bounds__(256) void cvt_all(CvtArgs a) {
  const int bx = blockIdx.x;
  int seg = 0;
#pragma unroll
  for (int i = 1; i < 7; ++i) seg += (bx >= a.cum[i]) ? 1 : 0;
  const int off = (bx - a.cum[seg]) * 256 + threadIdx.x;
  float4 f = reinterpret_cast<const float4*>(a.src[seg])[off];
  union { u16 u[4]; uint64_t q; } o;
  o.u[0] = f2b(f.x); o.u[1] = f2b(f.y); o.u[2] = f2b(f.z); o.u[3] = f2b(f.w);
  reinterpret_cast<uint64_t*>(a.dst[seg])[off] = o.q;
}

// ---------------------------------------------------------------- GEMM  C = A @ W^T + bias
// 128x128 tile, BK=64, double-buffered LDS with XOR-chunk swizzle (T2),
// XCD-aware block swizzle (T1). 4 waves, each 64x64 out.
// MODE 0: z in {0,1,2} selects q,k,v.
//   z==0 -> q [B,H,S,dk] bf16, values pre-scaled by log2(e)/sqrt(dk)
//   z==1 -> k [B,H,S,dk] bf16
//   z==2 -> VT [B,H,dk,S] bf16 with keys PERMUTED within each 16-block:
//           swap bits 2<->3 of key index -> fattn's 32x32 PV A-fragment
//           (regs kc*8..kc*8+8) matches a contiguous b128 V read.
// MODE 1: out fp32 [4096][1024] (final projection).
template <int MODE>
__global__ __launch_bounds__(256) void gemm_bt(const u16* __restrict__ Abase,
                                               const u16* __restrict__ Wbase,
                                               const float* __restrict__ bias0,
                                               const float* __restrict__ bias1,
                                               const float* __restrict__ bias2,
                                               u16* __restrict__ outb,
                                               u16* __restrict__ vtout,
                                               float* __restrict__ outf) {
  __shared__ u16 As[2][128 * 64];          // 16KB per buffer, chunk-swizzled
  __shared__ u16 Bs[2][128 * 64];
  const int tid = threadIdx.x;
  const int lane = tid & 63;
  const int w = tid >> 6;
  const int wr = w >> 1, wc = w & 1;       // 2x2 wave grid, each wave 64x64

  // T1: XCD-aware bijective swizzle. nwg = 8*32 = 256 (%8==0).
  const int bid = blockIdx.y * 8 + blockIdx.x;
  const int sw = (bid & 7) * 32 + (bid >> 3);
  const int n0 = (sw & 7) * 128;
  const int m0 = (sw >> 3) * 128;
  const int z = (MODE == 0) ? blockIdx.z : 0;
  const float QSC = 0.18033688011112042f;  // log2(e) / sqrt(dk)

  const u16* A = Abase + (size_t)z * (4096u * 1024u);
  const u16* W = Wbase + (size_t)z * (1024u * 1024u);
  const float* bias = (MODE == 0) ? (z == 0 ? bias0 : (z == 1 ? bias1 : bias2)) : bias0;
  u16* ob = (MODE == 0) ? (outb + (size_t)z * (4096u * 1024u)) : nullptr;

  const int l15 = lane & 15, l4 = lane >> 4;

  // staging: wave w stages rows [w*32, w*32+32) of each matrix as 4 calls of
  // 8 rows. Per lane: row = base + lane/8, storage chunk = lane&7,
  // logical col = ((lane&7) ^ (row&7)) * 8 elements.
  const int sr = lane >> 3;                 // 0..7 within 8-row group
  const int sx = lane & 7;                  // storage chunk
  const u16* gA[4];
  const u16* gB[4];
#pragma unroll
  for (int j = 0; j < 4; ++j) {
    const int row = w * 32 + j * 8 + sr;
    const int lc = ((sx ^ (row & 7)) << 3);
    gA[j] = A + (size_t)(m0 + row) * 1024 + lc;
    gB[j] = W + (size_t)(n0 + row) * 1024 + lc;
  }

  f32x4 acc[4][4];
#pragma unroll
  for (int i = 0; i < 4; ++i)
#pragma unroll
    for (int j = 0; j < 4; ++j) acc[i][j] = {0.f, 0.f, 0.f, 0.f};

  // prologue: stage K-tile 0
#pragma unroll
  for (int j = 0; j < 4; ++j) {
    stage16(gA[j], &As[0][(w * 32 + j * 8) * 64]);
    stage16(gB[j], &Bs[0][(w * 32 + j * 8) * 64]);
  }
  __syncthreads();

#pragma unroll 2
  for (int t = 0; t < 16; ++t) {
    const int cur = t & 1;
    if (t + 1 < 16) {                       // issue next tile; hides under MFMA
      const int kt = (t + 1) * 64;
#pragma unroll
      for (int j = 0; j < 4; ++j) {
        stage16(gA[j] + kt, &As[cur ^ 1][(w * 32 + j * 8) * 64]);
        stage16(gB[j] + kt, &Bs[cur ^ 1][(w * 32 + j * 8) * 64]);
      }
    }
#pragma unroll
    for (int ks = 0; ks < 2; ++ks) {
      s16x8 af[4], bf[4];
#pragma unroll
      for (int mi = 0; mi < 4; ++mi) {
        const int row = wr * 64 + mi * 16 + l15;
        const int sc_ = (((ks << 2) | l4) ^ (l15 & 7)) << 3;
        af[mi] = *(const s16x8*)&As[cur][row * 64 + sc_];
      }
#pragma unroll
      for (int ni = 0; ni < 4; ++ni) {
        const int row = wc * 64 + ni * 16 + l15;
        const int sc_ = (((ks << 2) | l4) ^ (l15 & 7)) << 3;
        bf[ni] = *(const s16x8*)&Bs[cur][row * 64 + sc_];
      }
      __builtin_amdgcn_s_setprio(1);
#pragma unroll
      for (int mi = 0; mi < 4; ++mi)
#pragma unroll
        for (int ni = 0; ni < 4; ++ni)
          acc[mi][ni] = mfma16(af[mi], bf[ni], acc[mi][ni]);
      __builtin_amdgcn_s_setprio(0);
    }
    __syncthreads();
  }

#pragma unroll
  for (int ni = 0; ni < 4; ++ni) {
    const int col = n0 + wc * 64 + ni * 16 + l15;
    const float bv = bias[col];
#pragma unroll
    for (int mi = 0; mi < 4; ++mi) {
      const int row0 = m0 + wr * 64 + mi * 16 + l4 * 4;
      if (MODE == 0 && z == 2) {
        // V -> VT [B,H,dk,S], permuted key order (swap bits 2<->3 of key idx)
        const int b = row0 >> 11, s0 = row0 & 2047;
        const int pos0 = (s0 & ~15) | ((s0 & 4) << 1) | ((s0 & 8) >> 1);
        const int h = col >> 6, d = col & 63;
        u16x4 pk = {f2b(acc[mi][ni][0] + bv), f2b(acc[mi][ni][1] + bv),
                    f2b(acc[mi][ni][2] + bv), f2b(acc[mi][ni][3] + bv)};
        *(u16x4*)&vtout[((size_t)(b * 16 + h) * 64 + d) * 2048 + pos0] = pk;
      } else {
#pragma unroll
        for (int r = 0; r < 4; ++r) {
          float val = acc[mi][ni][r] + bv;
          const int row = row0 + r;
          if (MODE == 0) {
            if (z == 0) val *= QSC;          // fold softmax scale into q
            const int b = row >> 11, s = row & 2047;
            const int h = col >> 6, d = col & 63;
            ob[((size_t)(b * 16 + h) * 2048 + s) * 64 + d] = f2b(val);
          } else {
            outf[(size_t)row * 1024 + col] = val;
          }
        }
      }
    }
  }
}

// ---------------------------------------------------------------- flash attention
// 4 waves x 64 q-rows (two 32x32 q-tiles each) = 256 q/block; grid (8,32) =
// 256 blocks = 1 block/CU = 4 waves/CU. RATIONALE: total wave count is fixed
// (1024); every wave must read the whole K/V tile, so CU-level DS traffic
// scales with waves/CU x tile. 64q/wave halves DS per score vs R8 -- each
// kf/vf b128 read feeds BOTH q-tiles. Simple 2-buffer, 1-barrier loop (R9's
// 3-buffer pipeline regressed); stage issued at iter top = full-iter cover.
// 32x32x16 MFMA, swapped QK^T (lane&31 owns one q per q-tile), P in-register
// with self-owned-key order (VT key-permuted in global). Denominator =
// in-lane adds + shfl_xor(32). Running max baked into C-init; THR=8
// defer-max (rare).
__global__ __launch_bounds__(256) void fattn(const u16* __restrict__ qp,
                                             const u16* __restrict__ kp,
                                             const u16* __restrict__ vt,
                                             u16* __restrict__ ao) {
  __shared__ u16 Kt[2][4096];               // 64 keys x 64 dk, chunk-swizzled
  __shared__ u16 Vt[2][4096];               // 64 d    x 64 keys (perm), chunk-swizzled

  const int lane = threadIdx.x & 63;
  const int w = threadIdx.x >> 6;           // 0..3
  const int bh = blockIdx.y;
  const int b = bh >> 4, h = bh & 15;
  const int q0 = blockIdx.x * 256 + w * 64;
  const u16* qb = qp + (size_t)bh * (2048 * 64);
  const u16* kb = kp + (size_t)bh * (2048 * 64);
  const u16* vb = vt + (size_t)bh * (64 * 2048);
  const int l31 = lane & 31, hl = lane >> 5;
  const int x7 = l31 & 7;
  const float THR = 8.0f;                   // defer-max threshold (T13), log2 units

  // staging: wave w stages rows [w*16, w*16+16) of each 8KB tile as 2 calls
  // of 8 rows. chunk s of row r holds logical col (s ^ (r&7))*8.
  const int srow = (w << 4) + (lane >> 3);
  const int c0 = (((lane & 7) ^ (srow & 7)) << 3);

  // Q fragments (persistent), per q-tile: B-operand of 32x32x16: col = q =
  // l31, k-slot (hl,j) = dk kc*16 + hl*8 + j. q pre-scaled by log2(e)/sqrt(dk).
  s16x8 qa0[4], qa1[4];
#pragma unroll
  for (int kc = 0; kc < 4; ++kc) {
    qa0[kc] = ld_g16(qb + (size_t)(q0 + l31) * 64 + kc * 16 + hl * 8);
    qa1[kc] = ld_g16(qb + (size_t)(q0 + 32 + l31) * 64 + kc * 16 + hl * 8);
  }

  f32x16 o00, o01, o10, o11;                // o{qt}{dt}; O[q][d=dt*32+l31]
  float lsum0 = 0.f, lsum1 = 0.f;           // denominators for q-tiles 0,1
  float mrun0 = 0.f, mrun1 = 0.f;           // running maxes
#pragma unroll
  for (int r = 0; r < 16; ++r) { o00[r] = 0.f; o01[r] = 0.f; o10[r] = 0.f; o11[r] = 0.f; }

  // prologue: stage tile 0
  stage16(kb + (size_t)srow * 64 + c0, &Kt[0][w * 1024]);
  stage16(kb + (size_t)(srow + 8) * 64 + c0, &Kt[0][w * 1024 + 512]);
  stage16(vb + (size_t)srow * 2048 + c0, &Vt[0][w * 1024]);
  stage16(vb + (size_t)(srow + 8) * 2048 + c0, &Vt[0][w * 1024 + 512]);
  __syncthreads();

#pragma unroll 2
  for (int t = 0; t < 32; ++t) {
    const int cur = t & 1;
    if (t + 1 < 32) {                       // issue next tile early (full-iter cover)
      const int kk = (t + 1) << 6;
      stage16(kb + (size_t)(kk + srow) * 64 + c0, &Kt[cur ^ 1][w * 1024]);
      stage16(kb + (size_t)(kk + srow + 8) * 64 + c0, &Kt[cur ^ 1][w * 1024 + 512]);
      stage16(vb + (size_t)srow * 2048 + kk + c0, &Vt[cur ^ 1][w * 1024]);
      stage16(vb + (size_t)(srow + 8) * 2048 + kk + c0, &Vt[cur ^ 1][w * 1024 + 512]);
    }

    // ---- QK^T (swapped, 32x32x16): s{qt}{nk} = D[key][q] - mrun (C-init bake)
    f32x16 s00, s01, s10, s11;
#pragma unroll
    for (int r = 0; r < 16; ++r) {
      s00[r] = -mrun0; s01[r] = -mrun0;
      s10[r] = -mrun1; s11[r] = -mrun1;
    }
#pragma unroll
    for (int nk = 0; nk < 2; ++nk) {
      s16x8 kf[4];
#pragma unroll
      for (int kc = 0; kc < 4; ++kc)
        kf[kc] = *(const s16x8*)&Kt[cur][(nk * 32 + l31) * 64 +
                                         ((((kc << 1) | hl) ^ x7) << 3)];
      __builtin_amdgcn_s_setprio(1);
      if (nk == 0) {
#pragma unroll
        for (int kc = 0; kc < 4; ++kc) s00 = mfma32(kf[kc], qa0[kc], s00);
#pragma unroll
        for (int kc = 0; kc < 4; ++kc) s10 = mfma32(kf[kc], qa1[kc], s10);
      } else {
#pragma unroll
        for (int kc = 0; kc < 4; ++kc) s01 = mfma32(kf[kc], qa0[kc], s01);
#pragma unroll
        for (int kc = 0; kc < 4; ++kc) s11 = mfma32(kf[kc], qa1[kc], s11);
      }
      __builtin_amdgcn_s_setprio(0);
    }

    // ---- per-q relative max (in-lane over 32 regs, then other-half xor 32)
    float m0 = fmaxf(s00[0], s00[1]);
#pragma unroll
    for (int r = 2; r < 16; r += 2) m0 = max3f(m0, s00[r], s00[r + 1]);
#pragma unroll
    for (int r = 0; r < 16; r += 2) m0 = max3f(m0, s01[r], s01[r + 1]);
    m0 = fmaxf(m0, __shfl_xor(m0, 32));
    float m1 = fmaxf(s10[0], s10[1]);
#pragma unroll
    for (int r = 2; r < 16; r += 2) m1 = max3f(m1, s10[r], s10[r + 1]);
#pragma unroll
    for (int r = 0; r < 16; r += 2) m1 = max3f(m1, s11[r], s11[r + 1]);
    m1 = fmaxf(m1, __shfl_xor(m1, 32));

    // ---- defer-max (T13): rare; in-place correction per q-tile
    if (__any(fmaxf(m0, m1) > THR)) {
      const float d0 = fmaxf(m0, 0.f);
      mrun0 += d0;
      const float al0 = EXP2F(-d0);
      lsum0 *= al0;
#pragma unroll
      for (int r = 0; r < 16; ++r) {
        float ar = __shfl(al0, (r & 3) + 8 * (r >> 2) + 4 * hl);
        o00[r] *= ar; o01[r] *= ar;
      }
#pragma unroll
      for (int r = 0; r < 16; ++r) { s00[r] -= d0; s01[r] -= d0; }
      const float d1 = fmaxf(m1, 0.f);
      mrun1 += d1;
      const float al1 = EXP2F(-d1);
      lsum1 *= al1;
#pragma unroll
      for (int r = 0; r < 16; ++r) {
        float ar = __shfl(al1, (r & 3) + 8 * (r >> 2) + 4 * hl);
        o10[r] *= ar; o11[r] *= ar;
      }
#pragma unroll
      for (int r = 0; r < 16; ++r) { s10[r] -= d1; s11[r] -= d1; }
    }

    // ---- P = exp2(sc), denominator adds, pack -> PV MFMA (V-frags shared
    // across both q-tiles; chunk = nk*4 + kc*2 + hl; VT key-permuted).
    // nk = 0:
    {
      float p0[16], p1[16];
#pragma unroll
      for (int r = 0; r < 16; ++r) p0[r] = EXP2F(s00[r]);
#pragma unroll
      for (int r = 0; r < 16; ++r) p1[r] = EXP2F(s10[r]);
#pragma unroll
      for (int r = 0; r < 16; ++r) { lsum0 += p0[r]; lsum1 += p1[r]; }
#pragma unroll
      for (int kc = 0; kc < 2; ++kc) {
        union { uint32_t d[4]; s16x8 v; } pa0, pa1;
        pa0.d[0] = cvtpk(p0[kc * 8 + 0], p0[kc * 8 + 1]);
        pa0.d[1] = cvtpk(p0[kc * 8 + 2], p0[kc * 8 + 3]);
        pa0.d[2] = cvtpk(p0[kc * 8 + 4], p0[kc * 8 + 5]);
        pa0.d[3] = cvtpk(p0[kc * 8 + 6], p0[kc * 8 + 7]);
        pa1.d[0] = cvtpk(p1[kc * 8 + 0], p1[kc * 8 + 1]);
        pa1.d[1] = cvtpk(p1[kc * 8 + 2], p1[kc * 8 + 3]);
        pa1.d[2] = cvtpk(p1[kc * 8 + 4], p1[kc * 8 + 5]);
        pa1.d[3] = cvtpk(p1[kc * 8 + 6], p1[kc * 8 + 7]);
        const int chunk = 0 * 4 + kc * 2 + hl;
        s16x8 vf0 = *(const s16x8*)&Vt[cur][(0 * 32 + l31) * 64 + ((chunk ^ x7) << 3)];
        s16x8 vf1 = *(const s16x8*)&Vt[cur][(1 * 32 + l31) * 64 + ((chunk ^ x7) << 3)];
        __builtin_amdgcn_s_setprio(1);
        o00 = mfma32(pa0.v, vf0, o00);
        o10 = mfma32(pa1.v, vf0, o10);
        o01 = mfma32(pa0.v, vf1, o01);
        o11 = mfma32(pa1.v, vf1, o11);
        __builtin_amdgcn_s_setprio(0);
      }
    }
    // nk = 1:
    {
      float p0[16], p1[16];
#pragma unroll
      for (int r = 0; r < 16; ++r) p0[r] = EXP2F(s01[r]);
#pragma unroll
      for (int r = 0; r < 16; ++r) p1[r] = EXP2F(s11[r]);
#pragma unroll
      for (int r = 0; r < 16; ++r) { lsum0 += p0[r]; lsum1 += p1[r]; }
#pragma unroll
      for (int kc = 0; kc < 2; ++kc) {
        union { uint32_t d[4]; s16x8 v; } pa0, pa1;
        pa0.d[0] = cvtpk(p0[kc * 8 + 0], p0[kc * 8 + 1]);
        pa0.d[1] = cvtpk(p0[kc * 8 + 2], p0[kc * 8 + 3]);
        pa0.d[2] = cvtpk(p0[kc * 8 + 4], p0[kc * 8 + 5]);
        pa0.d[3] = cvtpk(p0[kc * 8 + 6], p0[kc * 8 + 7]);
        pa1.d[0] = cvtpk(p1[kc * 8 + 0], p1[kc * 8 + 1]);
        pa1.d[1] = cvtpk(p1[kc * 8 + 2], p1[kc * 8 + 3]);
        pa1.d[2] = cvtpk(p1[kc * 8 + 4], p1[kc * 8 + 5]);
        pa1.d[3] = cvtpk(p1[kc * 8 + 6], p1[kc * 8 + 7]);
        const int chunk = 1 * 4 + kc * 2 + hl;
        s16x8 vf0 = *(const s16x8*)&Vt[cur][(0 * 32 + l31) * 64 + ((chunk ^ x7) << 3)];
        s16x8 vf1 = *(const s16x8*)&Vt[cur][(1 * 32 + l31) * 64 + ((chunk ^ x7) << 3)];
        __builtin_amdgcn_s_setprio(1);
        o00 = mfma32(pa0.v, vf0, o00);
        o10 = mfma32(pa1.v, vf0, o10);
        o01 = mfma32(pa0.v, vf1, o01);
        o11 = mfma32(pa1.v, vf1, o11);
        __builtin_amdgcn_s_setprio(0);
      }
    }

    __syncthreads();   // all reads of buf `cur` done; next-tile stage drained
  }

  // ---- epilogue: combine denominator halves, normalize, store
  lsum0 += __shfl_xor(lsum0, 32);
  lsum1 += __shfl_xor(lsum1, 32);
#pragma unroll
  for (int r = 0; r < 16; ++r) {
    const int qreg = (r & 3) + 8 * (r >> 2) + 4 * hl;
    const float inv0 = 1.0f / __shfl(lsum0, qreg);
    const float inv1 = 1.0f / __shfl(lsum1, qreg);
    const int row0 = b * 2048 + q0 + qreg;
    const int row1 = row0 + 32;
    ao[(size_t)row0 * 1024 + h * 64 + l31]      = f2b(o00[r] * inv0);
    ao[(size_t)row0 * 1024 + h * 64 + 32 + l31] = f2b(o01[r] * inv0);
    ao[(size_t)row1 * 1024 + h * 64 + l31]      = f2b(o10[r] * inv1);
    ao[(size_t)row1 * 1024 + h * 64 + 32 + l31] = f2b(o11[r] * inv1);
  }
}

// ---------------------------------------------------------------- host
extern "C" void kernel_launch(void* const* d_in, const int* in_sizes, int n_in,
                              void* d_out, int out_size, void* d_ws, size_t ws_size,
                              hipStream_t stream) {
  const float* Q  = (const float*)d_in[0];
  const float* K  = (const float*)d_in[1];
  const float* V  = (const float*)d_in[2];
  const float* Wq = (const float*)d_in[3];
  const float* bq = (const float*)d_in[4];
  const float* Wk = (const float*)d_in[5];
  const float* bk = (const float*)d_in[6];
  const float* Wv = (const float*)d_in[7];
  const float* bv = (const float*)d_in[8];
  const float* Wo = (const float*)d_in[9];
  const float* bo = (const float*)d_in[10];
  float* out = (float*)d_out;

  const size_t NI = (size_t)4096 * 1024;
  const size_t NW = (size_t)1024 * 1024;
  u16* XB  = (u16*)d_ws;          // Qb,Kb,Vb bf16 (3*NI)
  u16* WB  = XB + 3 * NI;         // Wq,Wk,Wv,Wo bf16 (4*NW)
  u16* QKV = WB + 4 * NW;         // q,k [B,H,S,dk] bf16 (slot 2 unused)
  u16* VT  = QKV + 3 * NI;        // vT [B,H,dk,S] bf16 (key-permuted)
  u16* AO  = VT + NI;             // attention output bf16 [B*S][D]

  CvtArgs ca;
  ca.src[0] = Q;  ca.dst[0] = XB;
  ca.src[1] = K;  ca.dst[1] = XB + NI;
  ca.src[2] = V;  ca.dst[2] = XB + 2 * NI;
  ca.src[3] = Wq; ca.dst[3] = WB;
  ca.src[4] = Wk; ca.dst[4] = WB + NW;
  ca.src[5] = Wv; ca.dst[5] = WB + 2 * NW;
  ca.src[6] = Wo; ca.dst[6] = WB + 3 * NW;
  ca.cum[0] = 0;     ca.cum[1] = 4096;  ca.cum[2] = 8192;  ca.cum[3] = 12288;
  ca.cum[4] = 13312; ca.cum[5] = 14336; ca.cum[6] = 15360; ca.cum[7] = 16384;
  cvt_all<<<dim3(16384), 256, 0, stream>>>(ca);

  // q,k,v projections (z = 0,1,2); z==0 pre-scales q; z==2 writes permuted VT
  gemm_bt<0><<<dim3(8, 32, 3), 256, 0, stream>>>(XB, WB, bq, bk, bv, QKV, VT, nullptr);
  // attention
  fattn<<<dim3(8, 32), 256, 0, stream>>>(QKV, QKV + NI, VT, AO);
  // output projection
  gemm_bt<1><<<dim3(8, 32, 1), 256, 0, stream>>>(AO, WB + 3 * NW, bo, nullptr, nullptr,
                                                 nullptr, nullptr, out);
}

// Round 12
// 121.407 us; speedup vs baseline: 1.1413x; 1.1413x over previous
//
#include <hip/hip_runtime.h>
#include <stdint.h>

// MultiHeadAttention fused pipeline for MI355X (gfx950).
// B=2, S=2048, D=1024, H=16, dk=64. fp32 in/out, bf16 MFMA compute.

#define AS1 __attribute__((address_space(1)))
#define AS3 __attribute__((address_space(3)))

typedef unsigned short u16;
typedef short s16x8 __attribute__((ext_vector_type(8)));   // 8 bf16 (4 VGPRs) MFMA frag
typedef float f32x4 __attribute__((ext_vector_type(4)));   // 16x16 MFMA accumulator
typedef float f32x16 __attribute__((ext_vector_type(16))); // 32x32 MFMA accumulator
typedef u16   u16x4 __attribute__((ext_vector_type(4)));

#if defined(__has_builtin)
#if __has_builtin(__builtin_amdgcn_exp2f)
#define EXP2F(x) __builtin_amdgcn_exp2f(x)
#else
#define EXP2F(x) exp2f(x)
#endif
#else
#define EXP2F(x) exp2f(x)
#endif

__device__ __forceinline__ u16 f2b(float f) {  // fp32 -> bf16 RNE
  union { float f; uint32_t u; } v;
  v.f = f;
  uint32_t r = (v.u + 0x7fffu + ((v.u >> 16) & 1u)) >> 16;
  return (u16)r;
}

// packed fp32x2 -> bf16x2 (1 VALU op; no builtin on gfx950 -> inline asm, T12)
__device__ __forceinline__ uint32_t cvtpk(float lo, float hi) {
  uint32_t r;
  asm("v_cvt_pk_bf16_f32 %0, %1, %2" : "=v"(r) : "v"(lo), "v"(hi));
  return r;
}

__device__ __forceinline__ float max3f(float a, float b, float c) {
  float r;
  asm("v_max3_f32 %0, %1, %2, %3" : "=v"(r) : "v"(a), "v"(b), "v"(c));
  return r;
}

__device__ __forceinline__ f32x4 mfma16(s16x8 a, s16x8 b, f32x4 c) {
  return __builtin_amdgcn_mfma_f32_16x16x32_bf16(a, b, c, 0, 0, 0);
}

__device__ __forceinline__ f32x16 mfma32(s16x8 a, s16x8 b, f32x16 c) {
  return __builtin_amdgcn_mfma_f32_32x32x16_bf16(a, b, c, 0, 0, 0);
}

__device__ __forceinline__ s16x8 ld_g16(const u16* p) {
  return *reinterpret_cast<const s16x8*>(p);
}

// async global->LDS, 16B per lane. LDS dest must be WAVE-UNIFORM base; HW adds lane*16.
// Global SOURCE is per-lane -> swizzled layouts via pre-swizzled source (m173).
__device__ __forceinline__ void stage16(const u16* g, u16* lds_base) {
  __builtin_amdgcn_global_load_lds((const AS1 unsigned int*)g,
                                   (AS3 unsigned int*)lds_base, 16, 0, 0);
}

// ---------------------------------------------------------------- fp32 -> bf16 (weights only)
struct CvtArgs {
  const float* src[4];
  u16* dst[4];
  int cum[5];   // cumulative block ranges (1024 blocks per 1M-elem weight)
};

__global__ __launch_bounds__(256) void cvt_all(CvtArgs a) {
  const int bx = blockIdx.x;
  int seg = 0;
#pragma unroll
  for (int i = 1; i < 4; ++i) seg += (bx >= a.cum[i]) ? 1 : 0;
  const int off = (bx - a.cum[seg]) * 256 + threadIdx.x;
  float4 f = reinterpret_cast<const float4*>(a.src[seg])[off];
  union { u16 u[4]; uint64_t q; } o;
  o.u[0] = f2b(f.x); o.u[1] = f2b(f.y); o.u[2] = f2b(f.z); o.u[3] = f2b(f.w);
  reinterpret_cast<uint64_t*>(a.dst[seg])[off] = o.q;
}

// ---------------------------------------------------------------- GEMM  C = A @ W^T + bias
// 128x128 tile, BK=64, double-buffered LDS with XOR-chunk swizzle (T2),
// XCD-aware block swizzle (T1). 4 waves, each 64x64 out.
// MODE 0: z in {0,1,2} selects q,k,v. A is the FP32 input (Q/K/V) — conversion
//   to bf16 is FUSED into staging: global_load fp32x8 -> cvt_pk -> ds_write_b128
//   to the exact LDS slot stage16 would fill (same swizzle geometry).
//   z==0 -> q [B,H,S,dk] bf16, values pre-scaled by log2(e)/sqrt(dk)
//   z==1 -> k [B,H,S,dk] bf16
//   z==2 -> VT [B,H,dk,S] bf16 with keys PERMUTED within each 16-block:
//           swap bits 2<->3 of key index -> fattn's 32x32 PV A-fragment
//           (regs kc*8..kc*8+8) matches a contiguous b128 V read.
// MODE 1: A is bf16 (AO), staged via global_load_lds; out fp32 [4096][1024].
template <int MODE>
__global__ __launch_bounds__(256) void gemm_bt(const float* __restrict__ Aq,
                                               const float* __restrict__ Ak,
                                               const float* __restrict__ Av,
                                               const u16* __restrict__ Abf,
                                               const u16* __restrict__ Wbase,
                                               const float* __restrict__ bias0,
                                               const float* __restrict__ bias1,
                                               const float* __restrict__ bias2,
                                               u16* __restrict__ outb,
                                               u16* __restrict__ vtout,
                                               float* __restrict__ outf) {
  __shared__ u16 As[2][128 * 64];          // 16KB per buffer, chunk-swizzled
  __shared__ u16 Bs[2][128 * 64];
  const int tid = threadIdx.x;
  const int lane = tid & 63;
  const int w = tid >> 6;
  const int wr = w >> 1, wc = w & 1;       // 2x2 wave grid, each wave 64x64

  // T1: XCD-aware bijective swizzle. nwg = 8*32 = 256 (%8==0).
  const int bid = blockIdx.y * 8 + blockIdx.x;
  const int sw = (bid & 7) * 32 + (bid >> 3);
  const int n0 = (sw & 7) * 128;
  const int m0 = (sw >> 3) * 128;
  const int z = (MODE == 0) ? blockIdx.z : 0;
  const float QSC = 0.18033688011112042f;  // log2(e) / sqrt(dk)

  const float* Af = (MODE == 0) ? (z == 0 ? Aq : (z == 1 ? Ak : Av)) : nullptr;
  const u16* W = Wbase + (size_t)z * (1024u * 1024u);
  const float* bias = (MODE == 0) ? (z == 0 ? bias0 : (z == 1 ? bias1 : bias2)) : bias0;
  u16* ob = (MODE == 0) ? (outb + (size_t)z * (4096u * 1024u)) : nullptr;

  const int l15 = lane & 15, l4 = lane >> 4;

  // staging: wave w stages rows [w*32, w*32+32) of each matrix as 4 calls of
  // 8 rows. Per lane: row = base + lane/8, storage chunk = lane&7,
  // logical col = ((lane&7) ^ (row&7)) * 8 elements. LDS write slot (u16):
  // (w*32+j*8)*64 + lane*8 (identical to stage16's lane*16B placement).
  const int sr = lane >> 3;                 // 0..7 within 8-row group
  const int sx = lane & 7;                  // storage chunk
  const float* gAf[4];
  const u16* gAb[4];
  const u16* gB[4];
#pragma unroll
  for (int j = 0; j < 4; ++j) {
    const int row = w * 32 + j * 8 + sr;
    const int lc = ((sx ^ (row & 7)) << 3);
    if (MODE == 0) gAf[j] = Af + (size_t)(m0 + row) * 1024 + lc;
    else           gAb[j] = Abf + (size_t)(m0 + row) * 1024 + lc;
    gB[j] = W + (size_t)(n0 + row) * 1024 + lc;
  }

  f32x4 acc[4][4];
#pragma unroll
  for (int i = 0; i < 4; ++i)
#pragma unroll
    for (int j = 0; j < 4; ++j) acc[i][j] = {0.f, 0.f, 0.f, 0.f};

  // prologue: stage K-tile 0
#pragma unroll
  for (int j = 0; j < 4; ++j) {
    if (MODE == 0) {
      float4 b0 = *(const float4*)gAf[j];
      float4 b1 = *(const float4*)(gAf[j] + 4);
      union { uint32_t d[4]; s16x8 v; } cv;
      cv.d[0] = cvtpk(b0.x, b0.y); cv.d[1] = cvtpk(b0.z, b0.w);
      cv.d[2] = cvtpk(b1.x, b1.y); cv.d[3] = cvtpk(b1.z, b1.w);
      *(s16x8*)&As[0][(w * 32 + j * 8) * 64 + lane * 8] = cv.v;
    } else {
      stage16(gAb[j], &As[0][(w * 32 + j * 8) * 64]);
    }
    stage16(gB[j], &Bs[0][(w * 32 + j * 8) * 64]);
  }
  __syncthreads();

#pragma unroll 2
  for (int t = 0; t < 16; ++t) {
    const int cur = t & 1;
    float4 a0[4], a1[4];
    const bool more = (t + 1 < 16);
    if (more) {                             // issue next tile; hides under MFMA
      const int kt = (t + 1) * 64;
      if (MODE == 0) {
#pragma unroll
        for (int j = 0; j < 4; ++j) {       // fp32 loads -> regs (cvt after compute)
          a0[j] = *(const float4*)(gAf[j] + kt);
          a1[j] = *(const float4*)(gAf[j] + kt + 4);
        }
      } else {
#pragma unroll
        for (int j = 0; j < 4; ++j)
          stage16(gAb[j] + kt, &As[cur ^ 1][(w * 32 + j * 8) * 64]);
      }
#pragma unroll
      for (int j = 0; j < 4; ++j)
        stage16(gB[j] + kt, &Bs[cur ^ 1][(w * 32 + j * 8) * 64]);
    }
#pragma unroll
    for (int ks = 0; ks < 2; ++ks) {
      s16x8 af[4], bf[4];
#pragma unroll
      for (int mi = 0; mi < 4; ++mi) {
        const int row = wr * 64 + mi * 16 + l15;
        const int sc_ = (((ks << 2) | l4) ^ (l15 & 7)) << 3;
        af[mi] = *(const s16x8*)&As[cur][row * 64 + sc_];
      }
#pragma unroll
      for (int ni = 0; ni < 4; ++ni) {
        const int row = wc * 64 + ni * 16 + l15;
        const int sc_ = (((ks << 2) | l4) ^ (l15 & 7)) << 3;
        bf[ni] = *(const s16x8*)&Bs[cur][row * 64 + sc_];
      }
      __builtin_amdgcn_s_setprio(1);
#pragma unroll
      for (int mi = 0; mi < 4; ++mi)
#pragma unroll
        for (int ni = 0; ni < 4; ++ni)
          acc[mi][ni] = mfma16(af[mi], bf[ni], acc[mi][ni]);
      __builtin_amdgcn_s_setprio(0);
    }
    if (more && MODE == 0) {                // convert + write next A tile (loads have landed)
#pragma unroll
      for (int j = 0; j < 4; ++j) {
        union { uint32_t d[4]; s16x8 v; } cv;
        cv.d[0] = cvtpk(a0[j].x, a0[j].y); cv.d[1] = cvtpk(a0[j].z, a0[j].w);
        cv.d[2] = cvtpk(a1[j].x, a1[j].y); cv.d[3] = cvtpk(a1[j].z, a1[j].w);
        *(s16x8*)&As[cur ^ 1][(w * 32 + j * 8) * 64 + lane * 8] = cv.v;
      }
    }
    __syncthreads();
  }

#pragma unroll
  for (int ni = 0; ni < 4; ++ni) {
    const int col = n0 + wc * 64 + ni * 16 + l15;
    const float bv = bias[col];
#pragma unroll
    for (int mi = 0; mi < 4; ++mi) {
      const int row0 = m0 + wr * 64 + mi * 16 + l4 * 4;
      if (MODE == 0 && z == 2) {
        // V -> VT [B,H,dk,S], permuted key order (swap bits 2<->3 of key idx)
        const int b = row0 >> 11, s0 = row0 & 2047;
        const int pos0 = (s0 & ~15) | ((s0 & 4) << 1) | ((s0 & 8) >> 1);
        const int h = col >> 6, d = col & 63;
        u16x4 pk = {f2b(acc[mi][ni][0] + bv), f2b(acc[mi][ni][1] + bv),
                    f2b(acc[mi][ni][2] + bv), f2b(acc[mi][ni][3] + bv)};
        *(u16x4*)&vtout[((size_t)(b * 16 + h) * 64 + d) * 2048 + pos0] = pk;
      } else {
#pragma unroll
        for (int r = 0; r < 4; ++r) {
          float val = acc[mi][ni][r] + bv;
          const int row = row0 + r;
          if (MODE == 0) {
            if (z == 0) val *= QSC;          // fold softmax scale into q
            const int b = row >> 11, s = row & 2047;
            const int h = col >> 6, d = col & 63;
            ob[((size_t)(b * 16 + h) * 2048 + s) * 64 + d] = f2b(val);
          } else {
            outf[(size_t)row * 1024 + col] = val;
          }
        }
      }
    }
  }
}

// ---------------------------------------------------------------- flash attention
// (Best-measured body: 51.0 us. R9 pipeline and R10 64q/wave both regressed.)
// 8 waves x 32 q-rows = 256 q/block; grid (8,32) = 256 blocks = 1 block/CU.
// 32x32x16 MFMA: 16 MFMAs/iter (8 QK^T + 8 PV). Swapped QK^T: sc = mfma32(K,Q),
// D col = q = lane&31 (lane owns one q), 32 keys in regs. PV uses P straight
// from regs (VT key order permuted in global: swap bits 2<->3 within
// 16-blocks matches reg->key map (r&3)+8*(r>>2)+4h). Denominator = in-lane
// fp32 adds + one shfl_xor(32). Running max baked into C-init; mrun starts 0;
// THR=8 defer-max rescale (rare).
__global__ __launch_bounds__(512, 2) void fattn(const u16* __restrict__ qp,
                                                const u16* __restrict__ kp,
                                                const u16* __restrict__ vt,
                                                u16* __restrict__ ao) {
  __shared__ u16 Kt[2][4096];               // 64 keys x 64 dk, chunk-swizzled
  __shared__ u16 Vt[2][4096];               // 64 d    x 64 keys (perm), chunk-swizzled

  const int lane = threadIdx.x & 63;
  const int w = threadIdx.x >> 6;           // 0..7
  const int bh = blockIdx.y;
  const int b = bh >> 4, h = bh & 15;
  const int q0 = blockIdx.x * 256 + w * 32;
  const u16* qb = qp + (size_t)bh * (2048 * 64);
  const u16* kb = kp + (size_t)bh * (2048 * 64);
  const u16* vb = vt + (size_t)bh * (64 * 2048);
  const int l31 = lane & 31, hl = lane >> 5;
  const int x7 = l31 & 7;                   // row&7 for all our LDS reads
  const float THR = 8.0f;                   // defer-max threshold (T13), log2 units

  // staging: wave w stages storage chunks [w*64, w*64+64) of each 8KB tile.
  // chunk s -> row s>>3, storage col s&7, logical col = (s&7) ^ (row&7).
  const int srow = (w << 3) + (lane >> 3);
  const int c0 = (((lane & 7) ^ (srow & 7)) << 3);   // logical col in elements

  // Q fragments (persistent): B-operand of 32x32x16: col = q = l31,
  // k-slot (hl,j) = dk kc*16 + hl*8 + j. q pre-scaled by log2(e)/sqrt(dk).
  s16x8 qa[4];
#pragma unroll
  for (int kc = 0; kc < 4; ++kc)
    qa[kc] = ld_g16(qb + (size_t)(q0 + l31) * 64 + kc * 16 + hl * 8);

  f32x16 o[2];                              // O[q=(reg&3)+8*(reg>>2)+4hl][d=dt*32+l31]
  float lsum = 0.f;                         // denominator for q = l31 (own keys)
  float mrun = 0.f;                         // running max for q = l31
#pragma unroll
  for (int r = 0; r < 16; ++r) { o[0][r] = 0.f; o[1][r] = 0.f; }

  // prologue: stage tile 0
  stage16(kb + (size_t)srow * 64 + c0, &Kt[0][w * 512]);
  stage16(vb + (size_t)srow * 2048 + c0, &Vt[0][w * 512]);
  __syncthreads();

#pragma unroll 2
  for (int t = 0; t < 32; ++t) {
    const int cur = t & 1;
    if (t + 1 < 32) {                       // issue next tile early
      const int kk = (t + 1) << 6;
      stage16(kb + (size_t)(kk + srow) * 64 + c0, &Kt[cur ^ 1][w * 512]);
      stage16(vb + (size_t)srow * 2048 + kk + c0, &Vt[cur ^ 1][w * 512]);
    }

    // ---- QK^T (swapped, 32x32x16): sc[nk] = D[key][q] - mrun (C-init bake)
    f32x16 sc[2];
#pragma unroll
    for (int r = 0; r < 16; ++r) { sc[0][r] = -mrun; sc[1][r] = -mrun; }
#pragma unroll
    for (int nk = 0; nk < 2; ++nk) {
      s16x8 kf[4];
#pragma unroll
      for (int kc = 0; kc < 4; ++kc)
        kf[kc] = *(const s16x8*)&Kt[cur][(nk * 32 + l31) * 64 +
                                         ((((kc << 1) | hl) ^ x7) << 3)];
      __builtin_amdgcn_s_setprio(1);
#pragma unroll
      for (int kc = 0; kc < 4; ++kc)
        sc[nk] = mfma32(kf[kc], qa[kc], sc[nk]);
      __builtin_amdgcn_s_setprio(0);
    }

    // ---- per-q relative max: in-lane over 32, then xor 32 (other key half)
    float m = -1e30f;
#pragma unroll
    for (int nk = 0; nk < 2; ++nk)
#pragma unroll
      for (int r = 0; r < 16; r += 2)
        m = max3f(m, sc[nk][r], sc[nk][r + 1]);
    m = fmaxf(m, __shfl_xor(m, 32));

    // ---- defer-max (T13): rare; uniform in-place correction
    if (__any(m > THR)) {
      const float d = fmaxf(m, 0.f);
      mrun += d;
      const float alpha = EXP2F(-d);
      lsum *= alpha;
#pragma unroll
      for (int r = 0; r < 16; ++r) { sc[0][r] -= d; sc[1][r] -= d; }
#pragma unroll
      for (int r = 0; r < 16; ++r) {
        float ar = __shfl(alpha, (r & 3) + 8 * (r >> 2) + 4 * hl);
        o[0][r] *= ar; o[1][r] *= ar;
      }
    }

    // ---- P = exp2(sc), denominator adds, pack regs -> PV MFMA
#pragma unroll
    for (int nk = 0; nk < 2; ++nk) {
      float p[16];
#pragma unroll
      for (int r = 0; r < 16; ++r) p[r] = EXP2F(sc[nk][r]);
#pragma unroll
      for (int r = 0; r < 16; ++r) lsum += p[r];
#pragma unroll
      for (int kc = 0; kc < 2; ++kc) {
        union { uint32_t d[4]; s16x8 v; } pa;
        pa.d[0] = cvtpk(p[kc * 8 + 0], p[kc * 8 + 1]);
        pa.d[1] = cvtpk(p[kc * 8 + 2], p[kc * 8 + 3]);
        pa.d[2] = cvtpk(p[kc * 8 + 4], p[kc * 8 + 5]);
        pa.d[3] = cvtpk(p[kc * 8 + 6], p[kc * 8 + 7]);
        const int chunk = nk * 4 + kc * 2 + hl;
#pragma unroll
        for (int dt = 0; dt < 2; ++dt) {
          s16x8 vf = *(const s16x8*)&Vt[cur][(dt * 32 + l31) * 64 +
                                             ((chunk ^ x7) << 3)];
          __builtin_amdgcn_s_setprio(1);
          o[dt] = mfma32(pa.v, vf, o[dt]);
          __builtin_amdgcn_s_setprio(0);
        }
      }
    }

    __syncthreads();   // all reads of buf `cur` done; next-tile stage drained
  }

  // ---- epilogue: combine denominator halves, normalize, store
  lsum += __shfl_xor(lsum, 32);
#pragma unroll
  for (int r = 0; r < 16; ++r) {
    const int qreg = (r & 3) + 8 * (r >> 2) + 4 * hl;
    const float inv = 1.0f / __shfl(lsum, qreg);
    const int row = b * 2048 + q0 + qreg;
#pragma unroll
    for (int dt = 0; dt < 2; ++dt)
      ao[(size_t)row * 1024 + h * 64 + dt * 32 + l31] = f2b(o[dt][r] * inv);
  }
}

// ---------------------------------------------------------------- host
extern "C" void kernel_launch(void* const* d_in, const int* in_sizes, int n_in,
                              void* d_out, int out_size, void* d_ws, size_t ws_size,
                              hipStream_t stream) {
  const float* Q  = (const float*)d_in[0];
  const float* K  = (const float*)d_in[1];
  const float* V  = (const float*)d_in[2];
  const float* Wq = (const float*)d_in[3];
  const float* bq = (const float*)d_in[4];
  const float* Wk = (const float*)d_in[5];
  const float* bk = (const float*)d_in[6];
  const float* Wv = (const float*)d_in[7];
  const float* bv = (const float*)d_in[8];
  const float* Wo = (const float*)d_in[9];
  const float* bo = (const float*)d_in[10];
  float* out = (float*)d_out;

  const size_t NI = (size_t)4096 * 1024;
  const size_t NW = (size_t)1024 * 1024;
  u16* WB  = (u16*)d_ws;          // Wq,Wk,Wv,Wo bf16 (4*NW)
  u16* QKV = WB + 4 * NW;         // q,k [B,H,S,dk] bf16 (slot 2 unused)
  u16* VT  = QKV + 3 * NI;        // vT [B,H,dk,S] bf16 (key-permuted)
  u16* AO  = VT + NI;             // attention output bf16 [B*S][D]

  CvtArgs ca;
  ca.src[0] = Wq; ca.dst[0] = WB;
  ca.src[1] = Wk; ca.dst[1] = WB + NW;
  ca.src[2] = Wv; ca.dst[2] = WB + 2 * NW;
  ca.src[3] = Wo; ca.dst[3] = WB + 3 * NW;
  ca.cum[0] = 0; ca.cum[1] = 1024; ca.cum[2] = 2048; ca.cum[3] = 3072; ca.cum[4] = 4096;
  cvt_all<<<dim3(4096), 256, 0, stream>>>(ca);

  // q,k,v projections (z = 0,1,2) with fused fp32->bf16 A-staging;
  // z==0 pre-scales q; z==2 writes permuted VT
  gemm_bt<0><<<dim3(8, 32, 3), 256, 0, stream>>>(Q, K, V, nullptr, WB, bq, bk, bv,
                                                 QKV, VT, nullptr);
  // attention
  fattn<<<dim3(8, 32), 512, 0, stream>>>(QKV, QKV + NI, VT, AO);
  // output projection
  gemm_bt<1><<<dim3(8, 32, 1), 256, 0, stream>>>(nullptr, nullptr, nullptr, AO,
                                                 WB + 3 * NW, bo, nullptr, nullptr,
                                                 nullptr, nullptr, out);
}